// Round 2
// 992.156 us; speedup vs baseline: 1.1711x; 1.1711x over previous
//
#include <hip/hip_runtime.h>
#include <math.h>
#include <string.h>

// ---------------- problem constants ----------------
constexpr int BB   = 2048;   // batch
constexpr int NW   = 151;    // windows
constexpr int NF   = 200;    // features
constexpr float BN_EPS = 1e-5f;

typedef __bf16 bf16x8 __attribute__((ext_vector_type(8)));
typedef float  f32x4  __attribute__((ext_vector_type(4)));
typedef unsigned short u16x8 __attribute__((ext_vector_type(8)));

__device__ __forceinline__ unsigned short f2bf(float f) {
  unsigned int u; memcpy(&u, &f, 4);
  unsigned int r = (u + 0x7FFFu + ((u >> 16) & 1u)) >> 16;   // RNE
  return (unsigned short)r;
}
__device__ __forceinline__ float bf2f(unsigned short u) {
  unsigned int x = ((unsigned int)u) << 16;
  float f; memcpy(&f, &x, 4);
  return f;
}

// ---------------------------------------------------------------------------
// f layer 1 via sliding-window recurrence:
//   h[b,0,c]   = sum_i W[c,i] * x[b, i+50]
//   h[b,n+1,c] = h[b,n,c] + W[c,n] * (x[b,n] - x[b,n+50])
// ---------------------------------------------------------------------------
__global__ __launch_bounds__(256) void f1scan_k(
  const float* __restrict__ x, const float* __restrict__ W,
  float* __restrict__ Df)
{
  __shared__ float Wt[150*51];
  __shared__ float xs[800];
  __shared__ float lso[3200];
  const int t  = threadIdx.x;
  const int b0 = blockIdx.x * 4;
  const int ch = blockIdx.y;
  const int bl = t >> 6;
  const int c  = t & 63;

  for (int idx = t; idx < 50*150; idx += 256) {
    int cl = idx / 150, k = idx % 150;
    Wt[k*51 + cl] = W[(ch*50 + cl)*150 + k];
  }
  for (int idx = t; idx < 800; idx += 256) {
    int b2 = idx / 200, j = idx % 200;
    xs[idx] = x[(b0 + b2)*200 + j];
  }
  __syncthreads();

  float h = 0.f;
  if (c < 50) {
    #pragma unroll 5
    for (int i = 0; i < 150; i++)
      h += Wt[i*51 + c] * xs[bl*200 + 50 + i];
  }

  for (int n0 = 0; n0 < NW; n0 += 16) {
    const int cs = (NW - n0 < 16) ? (NW - n0) : 16;
    if (c < 50) {
      for (int l = 0; l < cs; l++) {
        int n = n0 + l;
        lso[bl*800 + l*50 + c] = h;
        if (n < 150) h += Wt[n*51 + c] * (xs[bl*200 + n] - xs[bl*200 + n + 50]);
      }
    }
    __syncthreads();
    const int tot = 4*cs*50;
    for (int idx = t; idx < tot; idx += 256) {
      int b2 = idx / (cs*50), rem = idx % (cs*50);
      int l = rem / 50, cc = rem % 50;
      Df[((size_t)(b0+b2)*NW + n0 + l)*100 + ch*50 + cc] = lso[b2*800 + l*50 + cc];
    }
    __syncthreads();
  }
}

// ---------------------------------------------------------------------------
// Per-window BN stats (sum, sumsq) over (b, c).
// ---------------------------------------------------------------------------
template<int C>
__global__ __launch_bounds__(256) void bnstats_k(
  const float* __restrict__ H, float* __restrict__ stats)
{
  __shared__ float red[8];
  const int n = blockIdx.x, b0 = blockIdx.y * 256, t = threadIdx.x;
  float s1 = 0.f, s2 = 0.f;
  for (int idx = t; idx < 256*C; idx += 256) {
    int b = b0 + idx / C, cc = idx % C;
    float v = H[((size_t)b*NW + n)*C + cc];
    s1 += v; s2 += v*v;
  }
  #pragma unroll
  for (int off = 32; off; off >>= 1) {
    s1 += __shfl_down(s1, off); s2 += __shfl_down(s2, off);
  }
  if ((t & 63) == 0) { red[(t>>6)*2] = s1; red[(t>>6)*2+1] = s2; }
  __syncthreads();
  if (t == 0) {
    atomicAdd(&stats[2*n],   red[0]+red[2]+red[4]+red[6]);
    atomicAdd(&stats[2*n+1], red[1]+red[3]+red[5]+red[7]);
  }
}

// ---------------------------------------------------------------------------
// Weight pre-conversion: fp32 W[OUT][IN] -> padded split-bf16 Wb.
//   Wb[o*KP + k]         = bf16_hi(W[o][k])   (zero-padded to OUTP x KP)
//   Wb[total + o*KP + k] = bf16_lo(residual)
// ---------------------------------------------------------------------------
__global__ __launch_bounds__(256) void wcvt_k(
  const float* __restrict__ W, unsigned short* __restrict__ Wb,
  int OUT, int IN, int KP, int total)
{
  int idx = blockIdx.x*256 + threadIdx.x;
  if (idx >= total) return;
  int o = idx / KP, k = idx % KP;
  float v = (o < OUT && k < IN) ? W[o*IN + k] : 0.f;
  unsigned short hi = f2bf(v);
  float lo = v - bf2f(hi);
  Wb[idx] = hi;
  Wb[total + idx] = f2bf(lo);
}

// ---------------------------------------------------------------------------
// MFMA layer: per (window n, 128-batch chunk):  H = act(bn(X)) @ W^T
// LDS-free. A-fragments loaded straight from global, BN+act applied in
// registers, split into hi/lo bf16 so that 3 MFMAs give ~fp32 accuracy:
//   acc += a_hi*w_hi + a_lo*w_hi + a_hi*w_lo     (lo*lo term ~2^-18, dropped)
// MODE 0: raw sliding window of x (row = x[b, n..n+IN)).  MODE 2: BN+act.
// ACT: 1 = leaky relu, 2 = tanh.
// Also accumulates per-window (sum, sumsq) into statsOut (padded cols are
// exactly zero so they contribute nothing).
// ---------------------------------------------------------------------------
template<int IN, int OUT, int MODE, int ACT>
__global__ __launch_bounds__(256) void layer_mfma_k(
    const float* __restrict__ X, const unsigned short* __restrict__ Wb,
    const float* __restrict__ statsPrev, float* __restrict__ H,
    float* __restrict__ statsOut)
{
  constexpr int KP   = (IN + 31) & ~31;    // K padded to 32
  constexpr int OUTP = (OUT + 15) & ~15;   // N padded to 16
  constexpr int KC   = KP / 32;
  constexpr int NT   = OUTP / 16;
  constexpr int MT   = 2;                  // m-tiles per wave (8 tiles / 4 waves)

  __shared__ float red[8];
  const int n    = blockIdx.x;
  const int b0   = blockIdx.y * 128;
  const int t    = threadIdx.x;
  const int w    = t >> 6;
  const int lane = t & 63;
  const int l16  = lane & 15;
  const int quad = lane >> 4;

  float mean = 0.f, rstd = 1.f;
  if constexpr (MODE == 2) {
    const float cnt = (float)BB * (float)IN;
    mean = statsPrev[2*n] / cnt;
    float var = statsPrev[2*n+1] / cnt - mean*mean;
    rstd = rsqrtf(var + BN_EPS);
  }

  // ---- A fragments: global -> (BN+act) -> split bf16, all in registers ----
  bf16x8 af_hi[MT][KC], af_lo[MT][KC];
  #pragma unroll
  for (int mt = 0; mt < MT; mt++) {
    const int bb = b0 + (w*MT + mt)*16 + l16;
    const float* xr = (MODE == 0)
        ? (X + (size_t)bb*NF + n)
        : (X + ((size_t)bb*NW + n)*IN);
    #pragma unroll
    for (int kc = 0; kc < KC; kc++) {
      const int k0 = kc*32 + quad*8;
      float vv[8];
      if constexpr (MODE == 0) {
        #pragma unroll
        for (int j = 0; j < 8; j++) {
          int k = k0 + j;
          vv[j] = (k < IN) ? xr[k] : 0.f;
        }
      } else if constexpr (IN % 4 == 0) {
        #pragma unroll
        for (int g = 0; g < 2; g++) {
          int kg = k0 + 4*g;
          if (kg < IN) {               // IN%4==0 -> group fully valid
            float4 f = *(const float4*)(xr + kg);
            vv[4*g] = f.x; vv[4*g+1] = f.y; vv[4*g+2] = f.z; vv[4*g+3] = f.w;
          } else {
            vv[4*g] = 0.f; vv[4*g+1] = 0.f; vv[4*g+2] = 0.f; vv[4*g+3] = 0.f;
          }
        }
      } else if constexpr (IN % 2 == 0) {
        #pragma unroll
        for (int g = 0; g < 4; g++) {
          int kg = k0 + 2*g;
          if (kg < IN) {               // IN%2==0 -> pair fully valid
            float2 f = *(const float2*)(xr + kg);
            vv[2*g] = f.x; vv[2*g+1] = f.y;
          } else {
            vv[2*g] = 0.f; vv[2*g+1] = 0.f;
          }
        }
      } else {
        #pragma unroll
        for (int j = 0; j < 8; j++) {
          int k = k0 + j;
          vv[j] = (k < IN) ? xr[k] : 0.f;
        }
      }
      u16x8 hi, lo;
      #pragma unroll
      for (int j = 0; j < 8; j++) {
        bool valid = (k0 + j) < IN;
        float v;
        if constexpr (MODE == 0) {
          v = vv[j];
        } else {
          float z = (vv[j] - mean) * rstd;
          float a = (ACT == 1) ? ((z >= 0.f) ? z : 0.01f*z) : tanhf(z);
          v = valid ? a : 0.f;
        }
        unsigned short h16 = f2bf(v);
        hi[j] = h16;
        lo[j] = f2bf(v - bf2f(h16));
      }
      af_hi[mt][kc] = __builtin_bit_cast(bf16x8, hi);
      af_lo[mt][kc] = __builtin_bit_cast(bf16x8, lo);
    }
  }

  // ---- MFMA over n-tiles ----
  float s1 = 0.f, s2 = 0.f;
  #pragma unroll
  for (int nt = 0; nt < NT; nt++) {
    const int c = nt*16 + l16;
    f32x4 acc[MT];
    #pragma unroll
    for (int mt = 0; mt < MT; mt++) acc[mt] = (f32x4){0.f, 0.f, 0.f, 0.f};
    #pragma unroll
    for (int kc = 0; kc < KC; kc++) {
      const unsigned short* wp = Wb + (size_t)(nt*16 + l16)*KP + kc*32 + quad*8;
      bf16x8 wh = *(const bf16x8*)wp;
      bf16x8 wl = *(const bf16x8*)(wp + OUTP*KP);
      #pragma unroll
      for (int mt = 0; mt < MT; mt++) {
        acc[mt] = __builtin_amdgcn_mfma_f32_16x16x32_bf16(af_hi[mt][kc], wh, acc[mt], 0, 0, 0);
        acc[mt] = __builtin_amdgcn_mfma_f32_16x16x32_bf16(af_lo[mt][kc], wh, acc[mt], 0, 0, 0);
        acc[mt] = __builtin_amdgcn_mfma_f32_16x16x32_bf16(af_hi[mt][kc], wl, acc[mt], 0, 0, 0);
      }
    }
    #pragma unroll
    for (int mt = 0; mt < MT; mt++) {
      const int mrow = (w*MT + mt)*16 + quad*4;
      #pragma unroll
      for (int r = 0; r < 4; r++) {
        float v = acc[mt][r];
        s1 += v; s2 += v*v;          // padded cols are exactly 0 -> no bias
        if (c < OUT)
          H[((size_t)(b0 + mrow + r)*NW + n)*OUT + c] = v;
      }
    }
  }

  // ---- BN stats reduction ----
  #pragma unroll
  for (int off = 32; off; off >>= 1) {
    s1 += __shfl_down(s1, off); s2 += __shfl_down(s2, off);
  }
  if (lane == 0) { red[w*2] = s1; red[w*2+1] = s2; }
  __syncthreads();
  if (t == 0) {
    atomicAdd(&statsOut[2*n],   red[0]+red[2]+red[4]+red[6]);
    atomicAdd(&statsOut[2*n+1], red[1]+red[3]+red[5]+red[7]);
  }
}

// ---------------------------------------------------------------------------
// Per-(b,d): 1/max(||leaky(bn(h3))||_n, 1e-12)
// ---------------------------------------------------------------------------
__global__ __launch_bounds__(256) void normstats_k(
  const float* __restrict__ H, const float* __restrict__ stats,
  float* __restrict__ rinv)
{
  int idx = blockIdx.x*256 + threadIdx.x;   // over B*128
  int b = idx >> 7, d = idx & 127;
  const float cnt = (float)BB * 128.f;
  float s = 0.f;
  for (int n = 0; n < NW; n++) {
    float m = stats[2*n] / cnt;
    float var = stats[2*n+1] / cnt - m*m;
    float r = rsqrtf(var + BN_EPS);
    float v = H[((size_t)b*NW + n)*128 + d];
    float z = (v - m) * r;
    float lv = (z >= 0.f) ? z : 0.01f*z;
    s += lv*lv;
  }
  rinv[idx] = 1.f / fmaxf(sqrtf(s), 1e-12f);
}

// ---------------------------------------------------------------------------
// leaky(bn(h3)) * rinv -> bf16 output, padded row stride 160 per batch.
// Each thread handles 2 consecutive d -> one packed 4B store.
// ---------------------------------------------------------------------------
__global__ __launch_bounds__(256) void applynorm_bf_k(
  const float* __restrict__ H, const float* __restrict__ stats,
  const float* __restrict__ rinv, unsigned int* __restrict__ Ob)
{
  size_t idx = (size_t)blockIdx.x*256 + threadIdx.x;  // over B*NW*64
  int dh = (int)(idx & 63);
  size_t bn = idx >> 6;
  int n = (int)(bn % NW); int b = (int)(bn / NW);
  const float cnt = (float)BB * 128.f;
  float m = stats[2*n] / cnt;
  float var = stats[2*n+1] / cnt - m*m;
  float r = rsqrtf(var + BN_EPS);
  float2 v = *(const float2*)&H[(((size_t)b*NW + n) << 7) + 2*dh];
  float z0 = (v.x - m) * r, z1 = (v.y - m) * r;
  float l0 = (z0 >= 0.f) ? z0 : 0.01f*z0;
  float l1 = (z1 >= 0.f) ? z1 : 0.01f*z1;
  l0 *= rinv[(b << 7) + 2*dh];
  l1 *= rinv[(b << 7) + 2*dh + 1];
  unsigned int packed = (unsigned int)f2bf(l0) | ((unsigned int)f2bf(l1) << 16);
  Ob[((size_t)b*160 + n)*64 + dh] = packed;
}

__global__ void invperm_k(const int* __restrict__ perm, int* __restrict__ inv) {
  int j = threadIdx.x;
  if (j < NW) inv[perm[j]] = j;
}

// ---------------------------------------------------------------------------
// Final einsum via MFMA bf16: per b, T[m][n] = sum_d P[m,d] Q[n,d].
// ---------------------------------------------------------------------------
__global__ __launch_bounds__(256) void final_mfma_k(
  const unsigned short* __restrict__ Qb, const unsigned short* __restrict__ Pb,
  const int* __restrict__ inv, float* __restrict__ out)
{
  __shared__ int invs[NW];
  const int b    = blockIdx.x;
  const int t    = threadIdx.x;
  const int w    = t >> 6;
  const int lane = t & 63;
  const int l16  = lane & 15;
  const int quad = lane >> 4;
  for (int i = t; i < NW; i += 256) invs[i] = inv[i];
  __syncthreads();

  const __bf16* Qp = (const __bf16*)(Qb + (size_t)b*160*128);
  const __bf16* Pp = (const __bf16*)(Pb + (size_t)b*160*128);
  float* ob = out + (size_t)b*152*NW;
  const float NEG_BIG = -3.0e38f;

  for (int ti = w; ti < 10; ti += 4) {          // m-strips
    const int mbase = ti*16;
    bf16x8 af[4];
    #pragma unroll
    for (int kc = 0; kc < 4; kc++)
      af[kc] = *(const bf16x8*)(Pp + (mbase + l16)*128 + kc*32 + quad*8);
    for (int tj = 0; tj < 10; tj++) {           // n-tiles
      const int nbase = tj*16;
      f32x4 acc = {0.f, 0.f, 0.f, 0.f};
      #pragma unroll
      for (int kc = 0; kc < 4; kc++) {
        bf16x8 bf = *(const bf16x8*)(Qp + (nbase + l16)*128 + kc*32 + quad*8);
        acc = __builtin_amdgcn_mfma_f32_16x16x32_bf16(af[kc], bf, acc, 0, 0, 0);
      }
      const int n = nbase + l16;
      if (n < NW) {
        #pragma unroll
        for (int r = 0; r < 4; r++) {
          const int m = mbase + quad*4 + r;
          if (m < NW) {
            float v = acc[r] * 100.f;
            int orow = 1 + invs[m];
            if (m == n) {
              ob[(size_t)orow*NW + n] = NEG_BIG;
              ob[n] = v;
            } else {
              ob[(size_t)orow*NW + n] = v;
            }
          }
        }
      }
    }
  }
}

// ---------------------------------------------------------------------------
extern "C" void kernel_launch(void* const* d_in, const int* in_sizes, int n_in,
                              void* d_out, int out_size, void* d_ws, size_t ws_size,
                              hipStream_t stream) {
  const float* x   = (const float*)d_in[0];
  const float* gW0 = (const float*)d_in[1];
  const float* gW1 = (const float*)d_in[2];
  const float* gW2 = (const float*)d_in[3];
  const float* fW0 = (const float*)d_in[4];
  const float* fW1 = (const float*)d_in[5];
  const float* fW2 = (const float*)d_in[6];
  const int*  perm = (const int*)d_in[7];
  float* out = (float*)d_out;
  char* ws = (char*)d_ws;

  float* stats = (float*)ws;                       // 6 x 302 floats
  int*   inv   = (int*)(ws + 8192);
  float* rinvP = (float*)(ws + 16384);             // 2048*128 (used late)
  float* rinvQ = rinvP + 2048*128;
  float* Ag = (float*)(ws + 16384 + 2*1048576);    // h1g: 2048*151*50
  float* Bg = Ag + 15462400;                       // h2g: 2048*151*25
  float* Cg = Bg + 7731200;                        // h3g (raw)
  float* Df = Cg + 39583744;                       // h1f: 2048*151*100
  float* Ff = Df + 30924800;                       // h3f (raw)
  float* Ef = Ag;                                  // h2f reuses dead h1g
  unsigned short* Qb = (unsigned short*)Ag;        // bf16 query (over dead Ag)
  unsigned short* Pb = (unsigned short*)Df;        // bf16 pos   (over dead Df)

  // split-bf16 weights live in the rinvP area (dead until normstats_k):
  //   hi block then lo block per layer; sizes = OUTP*KP shorts each.
  unsigned short* Wbase = (unsigned short*)(ws + 16384);
  unsigned short* Wg1 = Wbase;            // 64x64   -> 2*4096
  unsigned short* Wg2 = Wbase + 8192;     // 32x64   -> 2*2048
  unsigned short* Wg3 = Wbase + 12288;    // 128x32  -> 2*4096
  unsigned short* Wf2 = Wbase + 20480;    // 64x128  -> 2*8192
  unsigned short* Wf3 = Wbase + 36864;    // 128x64  -> 2*8192  (ends 53248)

  float* sg1 = stats,        *sg2 = stats + 302,  *sg3 = stats + 604;
  float* sf1 = stats + 906,  *sf2 = stats + 1208, *sf3 = stats + 1510;

  hipMemsetAsync(stats, 0, 1812*sizeof(float), stream);
  invperm_k<<<1, 192, 0, stream>>>(perm, inv);

  // weight pre-conversion (tiny)
  wcvt_k<<<16, 256, 0, stream>>>(gW0, Wg1,  50,  50,  64, 4096);
  wcvt_k<<< 8, 256, 0, stream>>>(gW1, Wg2,  25,  50,  64, 2048);
  wcvt_k<<<16, 256, 0, stream>>>(gW2, Wg3, 128,  25,  32, 4096);
  wcvt_k<<<32, 256, 0, stream>>>(fW1, Wf2,  50, 100, 128, 8192);
  wcvt_k<<<32, 256, 0, stream>>>(fW2, Wf3, 128,  50,  64, 8192);

  // f layer 1 via sliding-window scan + separate stats pass
  f1scan_k<<<dim3(BB/4, 2), 256, 0, stream>>>(x, fW0, Df);
  bnstats_k<100><<<dim3(NW, 8), 256, 0, stream>>>(Df, sf1);

  dim3 gl2(NW, BB/128);
  layer_mfma_k< 50,  50, 0, 0><<<gl2, 256, 0, stream>>>(x,  Wg1, nullptr, Ag, sg1);
  layer_mfma_k< 50,  25, 2, 1><<<gl2, 256, 0, stream>>>(Ag, Wg2, sg1,     Bg, sg2);
  layer_mfma_k< 25, 128, 2, 1><<<gl2, 256, 0, stream>>>(Bg, Wg3, sg2,     Cg, sg3);
  layer_mfma_k<100,  50, 2, 2><<<gl2, 256, 0, stream>>>(Df, Wf2, sf1,     Ef, sf2);
  layer_mfma_k< 50, 128, 2, 1><<<gl2, 256, 0, stream>>>(Ef, Wf3, sf2,     Ff, sf3);

  // pos -> Pb (bf16), query -> Qb (bf16)
  normstats_k  <<<1024,  256, 0, stream>>>(Cg, sg3, rinvP);
  applynorm_bf_k<<<77312, 256, 0, stream>>>(Cg, sg3, rinvP, (unsigned int*)Pb);
  normstats_k  <<<1024,  256, 0, stream>>>(Ff, sf3, rinvQ);
  applynorm_bf_k<<<77312, 256, 0, stream>>>(Ff, sf3, rinvQ, (unsigned int*)Qb);

  final_mfma_k<<<BB, 256, 0, stream>>>(Qb, Pb, inv, out);
  (void)in_sizes; (void)n_in; (void)out_size; (void)ws_size;
}

// Round 3
// 944.706 us; speedup vs baseline: 1.2299x; 1.0502x over previous
//
#include <hip/hip_runtime.h>
#include <math.h>
#include <string.h>

// ---------------- problem constants ----------------
constexpr int BB   = 2048;   // batch
constexpr int NW   = 151;    // windows
constexpr int NF   = 200;    // features
constexpr float BN_EPS = 1e-5f;

typedef __bf16 bf16x8 __attribute__((ext_vector_type(8)));
typedef float  f32x4  __attribute__((ext_vector_type(4)));
typedef unsigned short u16x8 __attribute__((ext_vector_type(8)));

__device__ __forceinline__ unsigned short f2bf(float f) {
  unsigned int u; memcpy(&u, &f, 4);
  unsigned int r = (u + 0x7FFFu + ((u >> 16) & 1u)) >> 16;   // RNE
  return (unsigned short)r;
}
__device__ __forceinline__ float bf2f(unsigned short u) {
  unsigned int x = ((unsigned int)u) << 16;
  float f; memcpy(&f, &x, 4);
  return f;
}

// ---------------------------------------------------------------------------
// f layer 1 via sliding-window recurrence:
//   h[b,0,c]   = sum_i W[c,i] * x[b, i+50]
//   h[b,n+1,c] = h[b,n,c] + W[c,n] * (x[b,n] - x[b,n+50])
// ---------------------------------------------------------------------------
__global__ __launch_bounds__(256) void f1scan_k(
  const float* __restrict__ x, const float* __restrict__ W,
  float* __restrict__ Df)
{
  __shared__ float Wt[150*51];
  __shared__ float xs[800];
  __shared__ float lso[3200];
  const int t  = threadIdx.x;
  const int b0 = blockIdx.x * 4;
  const int ch = blockIdx.y;
  const int bl = t >> 6;
  const int c  = t & 63;

  for (int idx = t; idx < 50*150; idx += 256) {
    int cl = idx / 150, k = idx % 150;
    Wt[k*51 + cl] = W[(ch*50 + cl)*150 + k];
  }
  for (int idx = t; idx < 800; idx += 256) {
    int b2 = idx / 200, j = idx % 200;
    xs[idx] = x[(b0 + b2)*200 + j];
  }
  __syncthreads();

  float h = 0.f;
  if (c < 50) {
    #pragma unroll 5
    for (int i = 0; i < 150; i++)
      h += Wt[i*51 + c] * xs[bl*200 + 50 + i];
  }

  for (int n0 = 0; n0 < NW; n0 += 16) {
    const int cs = (NW - n0 < 16) ? (NW - n0) : 16;
    if (c < 50) {
      for (int l = 0; l < cs; l++) {
        int n = n0 + l;
        lso[bl*800 + l*50 + c] = h;
        if (n < 150) h += Wt[n*51 + c] * (xs[bl*200 + n] - xs[bl*200 + n + 50]);
      }
    }
    __syncthreads();
    const int tot = 4*cs*50;
    for (int idx = t; idx < tot; idx += 256) {
      int b2 = idx / (cs*50), rem = idx % (cs*50);
      int l = rem / 50, cc = rem % 50;
      Df[((size_t)(b0+b2)*NW + n0 + l)*100 + ch*50 + cc] = lso[b2*800 + l*50 + cc];
    }
    __syncthreads();
  }
}

// ---------------------------------------------------------------------------
// Per-window BN stats (sum, sumsq) over (b, c).
// ---------------------------------------------------------------------------
template<int C>
__global__ __launch_bounds__(256) void bnstats_k(
  const float* __restrict__ H, float* __restrict__ stats)
{
  __shared__ float red[8];
  const int n = blockIdx.x, b0 = blockIdx.y * 256, t = threadIdx.x;
  float s1 = 0.f, s2 = 0.f;
  for (int idx = t; idx < 256*C; idx += 256) {
    int b = b0 + idx / C, cc = idx % C;
    float v = H[((size_t)b*NW + n)*C + cc];
    s1 += v; s2 += v*v;
  }
  #pragma unroll
  for (int off = 32; off; off >>= 1) {
    s1 += __shfl_down(s1, off); s2 += __shfl_down(s2, off);
  }
  if ((t & 63) == 0) { red[(t>>6)*2] = s1; red[(t>>6)*2+1] = s2; }
  __syncthreads();
  if (t == 0) {
    atomicAdd(&stats[2*n],   red[0]+red[2]+red[4]+red[6]);
    atomicAdd(&stats[2*n+1], red[1]+red[3]+red[5]+red[7]);
  }
}

// ---------------------------------------------------------------------------
// Weight pre-conversion: fp32 W[OUT][IN] -> padded split-bf16 Wb.
// ---------------------------------------------------------------------------
__global__ __launch_bounds__(256) void wcvt_k(
  const float* __restrict__ W, unsigned short* __restrict__ Wb,
  int OUT, int IN, int KP, int total)
{
  int idx = blockIdx.x*256 + threadIdx.x;
  if (idx >= total) return;
  int o = idx / KP, k = idx % KP;
  float v = (o < OUT && k < IN) ? W[o*IN + k] : 0.f;
  unsigned short hi = f2bf(v);
  float lo = v - bf2f(hi);
  Wb[idx] = hi;
  Wb[total + idx] = f2bf(lo);
}

// ---------------------------------------------------------------------------
// MFMA layer: per (window n, 128-batch chunk):  H = act(bn(X)) @ W^T
// LDS-free; split-bf16 (hi/lo) x3 MFMAs for ~fp32 accuracy.
// ---------------------------------------------------------------------------
template<int IN, int OUT, int MODE, int ACT>
__global__ __launch_bounds__(256) void layer_mfma_k(
    const float* __restrict__ X, const unsigned short* __restrict__ Wb,
    const float* __restrict__ statsPrev, float* __restrict__ H,
    float* __restrict__ statsOut)
{
  constexpr int KP   = (IN + 31) & ~31;    // K padded to 32
  constexpr int OUTP = (OUT + 15) & ~15;   // N padded to 16
  constexpr int KC   = KP / 32;
  constexpr int NT   = OUTP / 16;
  constexpr int MT   = 2;                  // m-tiles per wave

  __shared__ float red[8];
  const int n    = blockIdx.x;
  const int b0   = blockIdx.y * 128;
  const int t    = threadIdx.x;
  const int w    = t >> 6;
  const int lane = t & 63;
  const int l16  = lane & 15;
  const int quad = lane >> 4;

  float mean = 0.f, rstd = 1.f;
  if constexpr (MODE == 2) {
    const float cnt = (float)BB * (float)IN;
    mean = statsPrev[2*n] / cnt;
    float var = statsPrev[2*n+1] / cnt - mean*mean;
    rstd = rsqrtf(var + BN_EPS);
  }

  bf16x8 af_hi[MT][KC], af_lo[MT][KC];
  #pragma unroll
  for (int mt = 0; mt < MT; mt++) {
    const int bb = b0 + (w*MT + mt)*16 + l16;
    const float* xr = (MODE == 0)
        ? (X + (size_t)bb*NF + n)
        : (X + ((size_t)bb*NW + n)*IN);
    #pragma unroll
    for (int kc = 0; kc < KC; kc++) {
      const int k0 = kc*32 + quad*8;
      float vv[8];
      if constexpr (MODE == 0) {
        #pragma unroll
        for (int j = 0; j < 8; j++) {
          int k = k0 + j;
          vv[j] = (k < IN) ? xr[k] : 0.f;
        }
      } else if constexpr (IN % 4 == 0) {
        #pragma unroll
        for (int g = 0; g < 2; g++) {
          int kg = k0 + 4*g;
          if (kg < IN) {
            float4 f = *(const float4*)(xr + kg);
            vv[4*g] = f.x; vv[4*g+1] = f.y; vv[4*g+2] = f.z; vv[4*g+3] = f.w;
          } else {
            vv[4*g] = 0.f; vv[4*g+1] = 0.f; vv[4*g+2] = 0.f; vv[4*g+3] = 0.f;
          }
        }
      } else if constexpr (IN % 2 == 0) {
        #pragma unroll
        for (int g = 0; g < 4; g++) {
          int kg = k0 + 2*g;
          if (kg < IN) {
            float2 f = *(const float2*)(xr + kg);
            vv[2*g] = f.x; vv[2*g+1] = f.y;
          } else {
            vv[2*g] = 0.f; vv[2*g+1] = 0.f;
          }
        }
      } else {
        #pragma unroll
        for (int j = 0; j < 8; j++) {
          int k = k0 + j;
          vv[j] = (k < IN) ? xr[k] : 0.f;
        }
      }
      u16x8 hi, lo;
      #pragma unroll
      for (int j = 0; j < 8; j++) {
        bool valid = (k0 + j) < IN;
        float v;
        if constexpr (MODE == 0) {
          v = vv[j];
        } else {
          float z = (vv[j] - mean) * rstd;
          float a = (ACT == 1) ? ((z >= 0.f) ? z : 0.01f*z) : tanhf(z);
          v = valid ? a : 0.f;
        }
        unsigned short h16 = f2bf(v);
        hi[j] = h16;
        lo[j] = f2bf(v - bf2f(h16));
      }
      af_hi[mt][kc] = __builtin_bit_cast(bf16x8, hi);
      af_lo[mt][kc] = __builtin_bit_cast(bf16x8, lo);
    }
  }

  float s1 = 0.f, s2 = 0.f;
  #pragma unroll
  for (int nt = 0; nt < NT; nt++) {
    const int c = nt*16 + l16;
    f32x4 acc[MT];
    #pragma unroll
    for (int mt = 0; mt < MT; mt++) acc[mt] = (f32x4){0.f, 0.f, 0.f, 0.f};
    #pragma unroll
    for (int kc = 0; kc < KC; kc++) {
      const unsigned short* wp = Wb + (size_t)(nt*16 + l16)*KP + kc*32 + quad*8;
      bf16x8 wh = *(const bf16x8*)wp;
      bf16x8 wl = *(const bf16x8*)(wp + OUTP*KP);
      #pragma unroll
      for (int mt = 0; mt < MT; mt++) {
        acc[mt] = __builtin_amdgcn_mfma_f32_16x16x32_bf16(af_hi[mt][kc], wh, acc[mt], 0, 0, 0);
        acc[mt] = __builtin_amdgcn_mfma_f32_16x16x32_bf16(af_lo[mt][kc], wh, acc[mt], 0, 0, 0);
        acc[mt] = __builtin_amdgcn_mfma_f32_16x16x32_bf16(af_hi[mt][kc], wl, acc[mt], 0, 0, 0);
      }
    }
    #pragma unroll
    for (int mt = 0; mt < MT; mt++) {
      const int mrow = (w*MT + mt)*16 + quad*4;
      #pragma unroll
      for (int r = 0; r < 4; r++) {
        float v = acc[mt][r];
        s1 += v; s2 += v*v;
        if (c < OUT)
          H[((size_t)(b0 + mrow + r)*NW + n)*OUT + c] = v;
      }
    }
  }

  #pragma unroll
  for (int off = 32; off; off >>= 1) {
    s1 += __shfl_down(s1, off); s2 += __shfl_down(s2, off);
  }
  if (lane == 0) { red[w*2] = s1; red[w*2+1] = s2; }
  __syncthreads();
  if (t == 0) {
    atomicAdd(&statsOut[2*n],   red[0]+red[2]+red[4]+red[6]);
    atomicAdd(&statsOut[2*n+1], red[1]+red[3]+red[5]+red[7]);
  }
}

// ---------------------------------------------------------------------------
// Per-(b,d): 1/max(||leaky(bn(h3))||_n, 1e-12)
// ---------------------------------------------------------------------------
__global__ __launch_bounds__(256) void normstats_k(
  const float* __restrict__ H, const float* __restrict__ stats,
  float* __restrict__ rinv)
{
  int idx = blockIdx.x*256 + threadIdx.x;   // over B*128
  int b = idx >> 7, d = idx & 127;
  const float cnt = (float)BB * 128.f;
  float s = 0.f;
  for (int n = 0; n < NW; n++) {
    float m = stats[2*n] / cnt;
    float var = stats[2*n+1] / cnt - m*m;
    float r = rsqrtf(var + BN_EPS);
    float v = H[((size_t)b*NW + n)*128 + d];
    float z = (v - m) * r;
    float lv = (z >= 0.f) ? z : 0.01f*z;
    s += lv*lv;
  }
  rinv[idx] = 1.f / fmaxf(sqrtf(s), 1e-12f);
}

__global__ void invperm_k(const int* __restrict__ perm, int* __restrict__ inv) {
  int j = threadIdx.x;
  if (j < NW) inv[perm[j]] = j;
}

// ---------------------------------------------------------------------------
// Fused normalize + final einsum. One block per batch element b.
//  Phase 1: read h3 fp32 rows, BN+leaky, *rinv, f2bf (identical numerics to
//           the previous applynorm path) -> bf16 tiles in XOR-swizzled LDS.
//  Phase 2: T[m][n] = sum_d P[m,d] Q[n,d] via 16x16x32 bf16 MFMA from LDS.
//  Phase 3: stage 16-row output strips in LDS, write rows as contiguous
//           604B streams (fixes the 1.7x write amplification of scattered
//           64B segments at 4B alignment).
//   out[b,0,n] = T[n,n]*100 ; out[b,1+inv[m],n] = (m==n) ? NEG_BIG : T[m,n]*100
// ---------------------------------------------------------------------------
__global__ __launch_bounds__(256) void fusedfinal_k(
  const float* __restrict__ P32, const float* __restrict__ Q32,
  const float* __restrict__ sP, const float* __restrict__ sQ,
  const float* __restrict__ rinvP, const float* __restrict__ rinvQ,
  const int* __restrict__ inv, float* __restrict__ out)
{
  __shared__ unsigned short Pl[160*128];   // 40 KB, swizzled rows
  __shared__ unsigned short Ql[160*128];   // 40 KB
  __shared__ float stgbuf[4][16*161];      // 40.25 KB per-wave strip staging
  __shared__ int invs[NW];

  const int b    = blockIdx.x;
  const int t    = threadIdx.x;
  const int w    = t >> 6;
  const int lane = t & 63;
  const int l16  = lane & 15;
  const int quad = lane >> 4;
  const float cnt = (float)BB * 128.f;

  for (int i = t; i < NW; i += 256) invs[i] = inv[i];

  // zero pad rows 151..159 (both tiles), swizzled addresses
  for (int idx = t; idx < 9*32; idx += 256) {
    int row = 151 + idx/32, l = idx%32;
    unsigned int off = (unsigned int)(row*256 + l*8) ^ (unsigned int)((row&7)<<4);
    *(uint2*)((char*)Pl + off) = make_uint2(0u, 0u);
    *(uint2*)((char*)Ql + off) = make_uint2(0u, 0u);
  }

  // ---- phase 1: fill P and Q bf16 tiles ----
  {
    const int l32 = t & 31;          // 32 threads per row
    const int r8  = t >> 5;          // 8 rows in flight
    const int d0  = l32*4;
    const float4 riP = *(const float4*)&rinvP[(b<<7) + d0];
    const float4 riQ = *(const float4*)&rinvQ[(b<<7) + d0];
    for (int n = r8; n < NW; n += 8) {
      float mP = sP[2*n] / cnt;
      float vP = sP[2*n+1] / cnt - mP*mP;
      float rP = rsqrtf(vP + BN_EPS);
      float4 v = *(const float4*)&P32[((size_t)b*NW + n)*128 + d0];
      float z0=(v.x-mP)*rP, z1=(v.y-mP)*rP, z2=(v.z-mP)*rP, z3=(v.w-mP)*rP;
      z0 = ((z0>=0.f)?z0:0.01f*z0) * riP.x;
      z1 = ((z1>=0.f)?z1:0.01f*z1) * riP.y;
      z2 = ((z2>=0.f)?z2:0.01f*z2) * riP.z;
      z3 = ((z3>=0.f)?z3:0.01f*z3) * riP.w;
      unsigned int p0 = (unsigned int)f2bf(z0) | ((unsigned int)f2bf(z1) << 16);
      unsigned int p1 = (unsigned int)f2bf(z2) | ((unsigned int)f2bf(z3) << 16);
      unsigned int off = (unsigned int)(n*256 + d0*2) ^ (unsigned int)((n&7)<<4);
      *(uint2*)((char*)Pl + off) = make_uint2(p0, p1);

      float mQ = sQ[2*n] / cnt;
      float vQ = sQ[2*n+1] / cnt - mQ*mQ;
      float rQ = rsqrtf(vQ + BN_EPS);
      float4 u = *(const float4*)&Q32[((size_t)b*NW + n)*128 + d0];
      float y0=(u.x-mQ)*rQ, y1=(u.y-mQ)*rQ, y2=(u.z-mQ)*rQ, y3=(u.w-mQ)*rQ;
      y0 = ((y0>=0.f)?y0:0.01f*y0) * riQ.x;
      y1 = ((y1>=0.f)?y1:0.01f*y1) * riQ.y;
      y2 = ((y2>=0.f)?y2:0.01f*y2) * riQ.z;
      y3 = ((y3>=0.f)?y3:0.01f*y3) * riQ.w;
      unsigned int q0 = (unsigned int)f2bf(y0) | ((unsigned int)f2bf(y1) << 16);
      unsigned int q1 = (unsigned int)f2bf(y2) | ((unsigned int)f2bf(y3) << 16);
      *(uint2*)((char*)Ql + off) = make_uint2(q0, q1);
    }
  }
  __syncthreads();

  // ---- phase 2+3: MFMA strips + staged contiguous row writes ----
  float* ob = out + (size_t)b*152*NW;
  float* stg = stgbuf[w];
  const float NEG_BIG = -3.0e38f;

  for (int ti = w; ti < 10; ti += 4) {
    const int mbase = ti*16;
    bf16x8 af[4];
    #pragma unroll
    for (int kc = 0; kc < 4; kc++) {
      int row = mbase + l16;
      unsigned int off = (unsigned int)(row*256 + (kc*32+quad*8)*2)
                       ^ (unsigned int)((row&7)<<4);
      af[kc] = *(const bf16x8*)((const char*)Pl + off);
    }
    #pragma unroll 2
    for (int tj = 0; tj < 10; tj++) {
      f32x4 acc = {0.f, 0.f, 0.f, 0.f};
      #pragma unroll
      for (int kc = 0; kc < 4; kc++) {
        int row = tj*16 + l16;
        unsigned int off = (unsigned int)(row*256 + (kc*32+quad*8)*2)
                         ^ (unsigned int)((row&7)<<4);
        bf16x8 bf = *(const bf16x8*)((const char*)Ql + off);
        acc = __builtin_amdgcn_mfma_f32_16x16x32_bf16(af[kc], bf, acc, 0, 0, 0);
      }
      #pragma unroll
      for (int r = 0; r < 4; r++)
        stg[(quad*4 + r)*161 + tj*16 + l16] = acc[r];
    }
    // per-wave write of the 16-row strip; rows are contiguous 604B streams
    for (int r = 0; r < 16; r++) {
      const int mm = mbase + r;
      if (mm >= NW) break;
      const int orow = 1 + invs[mm];
      float* dst = ob + (size_t)orow*NW;
      for (int col = lane; col < NW; col += 64) {
        float v = stg[r*161 + col] * 100.f;
        if (col == mm) { ob[mm] = v; v = NEG_BIG; }
        dst[col] = v;
      }
    }
  }
}

// ---------------------------------------------------------------------------
extern "C" void kernel_launch(void* const* d_in, const int* in_sizes, int n_in,
                              void* d_out, int out_size, void* d_ws, size_t ws_size,
                              hipStream_t stream) {
  const float* x   = (const float*)d_in[0];
  const float* gW0 = (const float*)d_in[1];
  const float* gW1 = (const float*)d_in[2];
  const float* gW2 = (const float*)d_in[3];
  const float* fW0 = (const float*)d_in[4];
  const float* fW1 = (const float*)d_in[5];
  const float* fW2 = (const float*)d_in[6];
  const int*  perm = (const int*)d_in[7];
  float* out = (float*)d_out;
  char* ws = (char*)d_ws;

  float* stats = (float*)ws;                       // 6 x 302 floats
  int*   inv   = (int*)(ws + 8192);
  float* rinvP = (float*)(ws + 16384);             // 2048*128 (used late)
  float* rinvQ = rinvP + 2048*128;
  float* Ag = (float*)(ws + 16384 + 2*1048576);    // h1g: 2048*151*50
  float* Bg = Ag + 15462400;                       // h2g: 2048*151*25
  float* Cg = Bg + 7731200;                        // h3g (raw)
  float* Df = Cg + 39583744;                       // h1f: 2048*151*100
  float* Ff = Df + 30924800;                       // h3f (raw)
  float* Ef = Ag;                                  // h2f reuses dead h1g

  // split-bf16 weights live in the rinvP area (dead until normstats_k):
  unsigned short* Wbase = (unsigned short*)(ws + 16384);
  unsigned short* Wg1 = Wbase;            // 64x64   -> 2*4096
  unsigned short* Wg2 = Wbase + 8192;     // 32x64   -> 2*2048
  unsigned short* Wg3 = Wbase + 12288;    // 128x32  -> 2*4096
  unsigned short* Wf2 = Wbase + 20480;    // 64x128  -> 2*8192
  unsigned short* Wf3 = Wbase + 36864;    // 128x64  -> 2*8192  (ends 53248)

  float* sg1 = stats,        *sg2 = stats + 302,  *sg3 = stats + 604;
  float* sf1 = stats + 906,  *sf2 = stats + 1208, *sf3 = stats + 1510;

  hipMemsetAsync(stats, 0, 1812*sizeof(float), stream);
  invperm_k<<<1, 192, 0, stream>>>(perm, inv);

  // weight pre-conversion (tiny)
  wcvt_k<<<16, 256, 0, stream>>>(gW0, Wg1,  50,  50,  64, 4096);
  wcvt_k<<< 8, 256, 0, stream>>>(gW1, Wg2,  25,  50,  64, 2048);
  wcvt_k<<<16, 256, 0, stream>>>(gW2, Wg3, 128,  25,  32, 4096);
  wcvt_k<<<32, 256, 0, stream>>>(fW1, Wf2,  50, 100, 128, 8192);
  wcvt_k<<<32, 256, 0, stream>>>(fW2, Wf3, 128,  50,  64, 8192);

  // f layer 1 via sliding-window scan + separate stats pass
  f1scan_k<<<dim3(BB/4, 2), 256, 0, stream>>>(x, fW0, Df);
  bnstats_k<100><<<dim3(NW, 8), 256, 0, stream>>>(Df, sf1);

  dim3 gl2(NW, BB/128);
  layer_mfma_k< 50,  50, 0, 0><<<gl2, 256, 0, stream>>>(x,  Wg1, nullptr, Ag, sg1);
  layer_mfma_k< 50,  25, 2, 1><<<gl2, 256, 0, stream>>>(Ag, Wg2, sg1,     Bg, sg2);
  layer_mfma_k< 25, 128, 2, 1><<<gl2, 256, 0, stream>>>(Bg, Wg3, sg2,     Cg, sg3);
  layer_mfma_k<100,  50, 2, 2><<<gl2, 256, 0, stream>>>(Df, Wf2, sf1,     Ef, sf2);
  layer_mfma_k< 50, 128, 2, 1><<<gl2, 256, 0, stream>>>(Ef, Wf3, sf2,     Ff, sf3);

  // per-(b,d) inverse norms
  normstats_k<<<1024, 256, 0, stream>>>(Cg, sg3, rinvP);
  normstats_k<<<1024, 256, 0, stream>>>(Ff, sf3, rinvQ);

  // fused normalize + einsum + masked scatter
  fusedfinal_k<<<BB, 256, 0, stream>>>(Cg, Ff, sg3, sf3, rinvP, rinvQ, inv, out);
  (void)in_sizes; (void)n_in; (void)out_size; (void)ws_size;
}

// Round 4
// 841.798 us; speedup vs baseline: 1.3803x; 1.1222x over previous
//
#include <hip/hip_runtime.h>
#include <math.h>
#include <string.h>

// ---------------- problem constants ----------------
constexpr int BB   = 2048;   // batch
constexpr int NW   = 151;    // windows
constexpr int NF   = 200;    // features
constexpr float BN_EPS = 1e-5f;

typedef __bf16 bf16x8 __attribute__((ext_vector_type(8)));
typedef float  f32x4  __attribute__((ext_vector_type(4)));
typedef unsigned short u16x8 __attribute__((ext_vector_type(8)));

__device__ __forceinline__ unsigned short f2bf(float f) {
  unsigned int u; memcpy(&u, &f, 4);
  unsigned int r = (u + 0x7FFFu + ((u >> 16) & 1u)) >> 16;   // RNE
  return (unsigned short)r;
}
__device__ __forceinline__ float bf2f(unsigned short u) {
  unsigned int x = ((unsigned int)u) << 16;
  float f; memcpy(&f, &x, 4);
  return f;
}

// ---------------------------------------------------------------------------
// f layer 1 via sliding-window recurrence:
//   h[b,0,c]   = sum_i W[c,i] * x[b, i+50]
//   h[b,n+1,c] = h[b,n,c] + W[c,n] * (x[b,n] - x[b,n+50])
// ---------------------------------------------------------------------------
__global__ __launch_bounds__(256) void f1scan_k(
  const float* __restrict__ x, const float* __restrict__ W,
  float* __restrict__ Df)
{
  __shared__ float Wt[150*51];
  __shared__ float xs[800];
  __shared__ float lso[3200];
  const int t  = threadIdx.x;
  const int b0 = blockIdx.x * 4;
  const int ch = blockIdx.y;
  const int bl = t >> 6;
  const int c  = t & 63;

  for (int idx = t; idx < 50*150; idx += 256) {
    int cl = idx / 150, k = idx % 150;
    Wt[k*51 + cl] = W[(ch*50 + cl)*150 + k];
  }
  for (int idx = t; idx < 800; idx += 256) {
    int b2 = idx / 200, j = idx % 200;
    xs[idx] = x[(b0 + b2)*200 + j];
  }
  __syncthreads();

  float h = 0.f;
  if (c < 50) {
    #pragma unroll 5
    for (int i = 0; i < 150; i++)
      h += Wt[i*51 + c] * xs[bl*200 + 50 + i];
  }

  for (int n0 = 0; n0 < NW; n0 += 16) {
    const int cs = (NW - n0 < 16) ? (NW - n0) : 16;
    if (c < 50) {
      for (int l = 0; l < cs; l++) {
        int n = n0 + l;
        lso[bl*800 + l*50 + c] = h;
        if (n < 150) h += Wt[n*51 + c] * (xs[bl*200 + n] - xs[bl*200 + n + 50]);
      }
    }
    __syncthreads();
    const int tot = 4*cs*50;
    for (int idx = t; idx < tot; idx += 256) {
      int b2 = idx / (cs*50), rem = idx % (cs*50);
      int l = rem / 50, cc = rem % 50;
      Df[((size_t)(b0+b2)*NW + n0 + l)*100 + ch*50 + cc] = lso[b2*800 + l*50 + cc];
    }
    __syncthreads();
  }
}

// ---------------------------------------------------------------------------
// Per-window BN stats (sum, sumsq) over (b, c).
// ---------------------------------------------------------------------------
template<int C>
__global__ __launch_bounds__(256) void bnstats_k(
  const float* __restrict__ H, float* __restrict__ stats)
{
  __shared__ float red[8];
  const int n = blockIdx.x, b0 = blockIdx.y * 256, t = threadIdx.x;
  float s1 = 0.f, s2 = 0.f;
  for (int idx = t; idx < 256*C; idx += 256) {
    int b = b0 + idx / C, cc = idx % C;
    float v = H[((size_t)b*NW + n)*C + cc];
    s1 += v; s2 += v*v;
  }
  #pragma unroll
  for (int off = 32; off; off >>= 1) {
    s1 += __shfl_down(s1, off); s2 += __shfl_down(s2, off);
  }
  if ((t & 63) == 0) { red[(t>>6)*2] = s1; red[(t>>6)*2+1] = s2; }
  __syncthreads();
  if (t == 0) {
    atomicAdd(&stats[2*n],   red[0]+red[2]+red[4]+red[6]);
    atomicAdd(&stats[2*n+1], red[1]+red[3]+red[5]+red[7]);
  }
}

// ---------------------------------------------------------------------------
// Weight pre-conversion: fp32 W[OUT][IN] -> padded split-bf16 Wb.
// ---------------------------------------------------------------------------
__global__ __launch_bounds__(256) void wcvt_k(
  const float* __restrict__ W, unsigned short* __restrict__ Wb,
  int OUT, int IN, int KP, int total)
{
  int idx = blockIdx.x*256 + threadIdx.x;
  if (idx >= total) return;
  int o = idx / KP, k = idx % KP;
  float v = (o < OUT && k < IN) ? W[o*IN + k] : 0.f;
  unsigned short hi = f2bf(v);
  float lo = v - bf2f(hi);
  Wb[idx] = hi;
  Wb[total + idx] = f2bf(lo);
}

// ---------------------------------------------------------------------------
// MFMA layer: per (window n, 128-batch chunk):  H = act(bn(X)) @ W^T
// LDS-free; split-bf16 (hi/lo) x3 MFMAs for ~fp32 accuracy.
// ---------------------------------------------------------------------------
template<int IN, int OUT, int MODE, int ACT>
__global__ __launch_bounds__(256) void layer_mfma_k(
    const float* __restrict__ X, const unsigned short* __restrict__ Wb,
    const float* __restrict__ statsPrev, float* __restrict__ H,
    float* __restrict__ statsOut)
{
  constexpr int KP   = (IN + 31) & ~31;    // K padded to 32
  constexpr int OUTP = (OUT + 15) & ~15;   // N padded to 16
  constexpr int KC   = KP / 32;
  constexpr int NT   = OUTP / 16;
  constexpr int MT   = 2;                  // m-tiles per wave

  __shared__ float red[8];
  const int n    = blockIdx.x;
  const int b0   = blockIdx.y * 128;
  const int t    = threadIdx.x;
  const int w    = t >> 6;
  const int lane = t & 63;
  const int l16  = lane & 15;
  const int quad = lane >> 4;

  float mean = 0.f, rstd = 1.f;
  if constexpr (MODE == 2) {
    const float cnt = (float)BB * (float)IN;
    mean = statsPrev[2*n] / cnt;
    float var = statsPrev[2*n+1] / cnt - mean*mean;
    rstd = rsqrtf(var + BN_EPS);
  }

  bf16x8 af_hi[MT][KC], af_lo[MT][KC];
  #pragma unroll
  for (int mt = 0; mt < MT; mt++) {
    const int bb = b0 + (w*MT + mt)*16 + l16;
    const float* xr = (MODE == 0)
        ? (X + (size_t)bb*NF + n)
        : (X + ((size_t)bb*NW + n)*IN);
    #pragma unroll
    for (int kc = 0; kc < KC; kc++) {
      const int k0 = kc*32 + quad*8;
      float vv[8];
      if constexpr (MODE == 0) {
        #pragma unroll
        for (int j = 0; j < 8; j++) {
          int k = k0 + j;
          vv[j] = (k < IN) ? xr[k] : 0.f;
        }
      } else if constexpr (IN % 4 == 0) {
        #pragma unroll
        for (int g = 0; g < 2; g++) {
          int kg = k0 + 4*g;
          if (kg < IN) {
            float4 f = *(const float4*)(xr + kg);
            vv[4*g] = f.x; vv[4*g+1] = f.y; vv[4*g+2] = f.z; vv[4*g+3] = f.w;
          } else {
            vv[4*g] = 0.f; vv[4*g+1] = 0.f; vv[4*g+2] = 0.f; vv[4*g+3] = 0.f;
          }
        }
      } else if constexpr (IN % 2 == 0) {
        #pragma unroll
        for (int g = 0; g < 4; g++) {
          int kg = k0 + 2*g;
          if (kg < IN) {
            float2 f = *(const float2*)(xr + kg);
            vv[2*g] = f.x; vv[2*g+1] = f.y;
          } else {
            vv[2*g] = 0.f; vv[2*g+1] = 0.f;
          }
        }
      } else {
        #pragma unroll
        for (int j = 0; j < 8; j++) {
          int k = k0 + j;
          vv[j] = (k < IN) ? xr[k] : 0.f;
        }
      }
      u16x8 hi, lo;
      #pragma unroll
      for (int j = 0; j < 8; j++) {
        bool valid = (k0 + j) < IN;
        float v;
        if constexpr (MODE == 0) {
          v = vv[j];
        } else {
          float z = (vv[j] - mean) * rstd;
          float a = (ACT == 1) ? ((z >= 0.f) ? z : 0.01f*z) : tanhf(z);
          v = valid ? a : 0.f;
        }
        unsigned short h16 = f2bf(v);
        hi[j] = h16;
        lo[j] = f2bf(v - bf2f(h16));
      }
      af_hi[mt][kc] = __builtin_bit_cast(bf16x8, hi);
      af_lo[mt][kc] = __builtin_bit_cast(bf16x8, lo);
    }
  }

  float s1 = 0.f, s2 = 0.f;
  #pragma unroll
  for (int nt = 0; nt < NT; nt++) {
    const int c = nt*16 + l16;
    f32x4 acc[MT];
    #pragma unroll
    for (int mt = 0; mt < MT; mt++) acc[mt] = (f32x4){0.f, 0.f, 0.f, 0.f};
    #pragma unroll
    for (int kc = 0; kc < KC; kc++) {
      const unsigned short* wp = Wb + (size_t)(nt*16 + l16)*KP + kc*32 + quad*8;
      bf16x8 wh = *(const bf16x8*)wp;
      bf16x8 wl = *(const bf16x8*)(wp + OUTP*KP);
      #pragma unroll
      for (int mt = 0; mt < MT; mt++) {
        acc[mt] = __builtin_amdgcn_mfma_f32_16x16x32_bf16(af_hi[mt][kc], wh, acc[mt], 0, 0, 0);
        acc[mt] = __builtin_amdgcn_mfma_f32_16x16x32_bf16(af_lo[mt][kc], wh, acc[mt], 0, 0, 0);
        acc[mt] = __builtin_amdgcn_mfma_f32_16x16x32_bf16(af_hi[mt][kc], wl, acc[mt], 0, 0, 0);
      }
    }
    #pragma unroll
    for (int mt = 0; mt < MT; mt++) {
      const int mrow = (w*MT + mt)*16 + quad*4;
      #pragma unroll
      for (int r = 0; r < 4; r++) {
        float v = acc[mt][r];
        s1 += v; s2 += v*v;
        if (c < OUT)
          H[((size_t)(b0 + mrow + r)*NW + n)*OUT + c] = v;
      }
    }
  }

  #pragma unroll
  for (int off = 32; off; off >>= 1) {
    s1 += __shfl_down(s1, off); s2 += __shfl_down(s2, off);
  }
  if (lane == 0) { red[w*2] = s1; red[w*2+1] = s2; }
  __syncthreads();
  if (t == 0) {
    atomicAdd(&statsOut[2*n],   red[0]+red[2]+red[4]+red[6]);
    atomicAdd(&statsOut[2*n+1], red[1]+red[3]+red[5]+red[7]);
  }
}

// ---------------------------------------------------------------------------
// Per-(b,d): 1/max(||leaky(bn(h3))||_n, 1e-12)
// ---------------------------------------------------------------------------
__global__ __launch_bounds__(256) void normstats_k(
  const float* __restrict__ H, const float* __restrict__ stats,
  float* __restrict__ rinv)
{
  int idx = blockIdx.x*256 + threadIdx.x;   // over B*128
  int b = idx >> 7, d = idx & 127;
  const float cnt = (float)BB * 128.f;
  float s = 0.f;
  for (int n = 0; n < NW; n++) {
    float m = stats[2*n] / cnt;
    float var = stats[2*n+1] / cnt - m*m;
    float r = rsqrtf(var + BN_EPS);
    float v = H[((size_t)b*NW + n)*128 + d];
    float z = (v - m) * r;
    float lv = (z >= 0.f) ? z : 0.01f*z;
    s += lv*lv;
  }
  rinv[idx] = 1.f / fmaxf(sqrtf(s), 1e-12f);
}

__global__ void invperm_k(const int* __restrict__ perm, int* __restrict__ inv) {
  int j = threadIdx.x;
  if (j < NW) inv[perm[j]] = j;
}

// ---------------------------------------------------------------------------
// Fused normalize + final einsum. One block per batch element b.
//  - Q tile only in LDS (reused by all waves, XOR-swizzled, 152 rows).
//  - A-fragments built per-strip straight from global fp32 (row-exclusive
//    per wave -> no reuse -> no LDS), identical numerics to previous path.
//  - Output strips staged in per-wave LDS (stride 154: quads land on bank
//    offsets {0,8,16,24} -> exact 2-way, free) then written as contiguous
//    604B row streams.
//  Rows >= NW are clamped to NW-1; their products only affect m/n >= NW,
//  which are never stored.
// LDS total ~79 KB -> 2 blocks/CU.
// ---------------------------------------------------------------------------
__global__ __launch_bounds__(256) void fusedfinal_k(
  const float* __restrict__ P32, const float* __restrict__ Q32,
  const float* __restrict__ sP, const float* __restrict__ sQ,
  const float* __restrict__ rinvP, const float* __restrict__ rinvQ,
  const int* __restrict__ inv, float* __restrict__ out)
{
  __shared__ unsigned short Ql[152*128];   // 38912 B, swizzled rows
  __shared__ float stgbuf[4][16*154];      // 39424 B per-wave strip staging
  __shared__ int invs[NW];

  const int b    = blockIdx.x;
  const int t    = threadIdx.x;
  const int w    = t >> 6;
  const int lane = t & 63;
  const int l16  = lane & 15;
  const int quad = lane >> 4;
  const float cnt = (float)BB * 128.f;

  for (int i = t; i < NW; i += 256) invs[i] = inv[i];

  // ---- phase 1: fill Q bf16 tile (BN + leaky + rinv + f2bf) ----
  {
    const int l32 = t & 31;          // 32 threads per row
    const int r8  = t >> 5;          // 8 rows in flight
    const int d0  = l32*4;
    const float4 riQ = *(const float4*)&rinvQ[(b<<7) + d0];
    for (int n = r8; n < NW; n += 8) {
      float mQ = sQ[2*n] / cnt;
      float vQ = sQ[2*n+1] / cnt - mQ*mQ;
      float rQ = rsqrtf(vQ + BN_EPS);
      float4 u = *(const float4*)&Q32[((size_t)b*NW + n)*128 + d0];
      float y0=(u.x-mQ)*rQ, y1=(u.y-mQ)*rQ, y2=(u.z-mQ)*rQ, y3=(u.w-mQ)*rQ;
      y0 = ((y0>=0.f)?y0:0.01f*y0) * riQ.x;
      y1 = ((y1>=0.f)?y1:0.01f*y1) * riQ.y;
      y2 = ((y2>=0.f)?y2:0.01f*y2) * riQ.z;
      y3 = ((y3>=0.f)?y3:0.01f*y3) * riQ.w;
      unsigned int q0 = (unsigned int)f2bf(y0) | ((unsigned int)f2bf(y1) << 16);
      unsigned int q1 = (unsigned int)f2bf(y2) | ((unsigned int)f2bf(y3) << 16);
      unsigned int off = (unsigned int)(n*256 + d0*2) ^ (unsigned int)((n&7)<<4);
      *(uint2*)((char*)Ql + off) = make_uint2(q0, q1);
    }
  }
  __syncthreads();

  // per-lane rinvP slice for A-fragment columns (fixed by quad)
  float riA[4][8];
  #pragma unroll
  for (int kc = 0; kc < 4; kc++) {
    const int c0 = kc*32 + quad*8;
    float4 r0 = *(const float4*)&rinvP[(b<<7) + c0];
    float4 r1 = *(const float4*)&rinvP[(b<<7) + c0 + 4];
    riA[kc][0]=r0.x; riA[kc][1]=r0.y; riA[kc][2]=r0.z; riA[kc][3]=r0.w;
    riA[kc][4]=r1.x; riA[kc][5]=r1.y; riA[kc][6]=r1.z; riA[kc][7]=r1.w;
  }

  // ---- phase 2+3: MFMA strips + staged contiguous row writes ----
  float* ob = out + (size_t)b*152*NW;
  float* stg = stgbuf[w];
  const float NEG_BIG = -3.0e38f;

  for (int ti = w; ti < 10; ti += 4) {
    const int mbase = ti*16;
    // A-fragment: global fp32 row -> BN + leaky + rinv -> bf16 (in regs)
    const int arow = (mbase + l16 < NW) ? (mbase + l16) : (NW-1);
    const float mP = sP[2*arow] / cnt;
    const float vP = sP[2*arow+1] / cnt - mP*mP;
    const float rP = rsqrtf(vP + BN_EPS);
    const float* prow = P32 + ((size_t)b*NW + arow)*128;
    bf16x8 af[4];
    #pragma unroll
    for (int kc = 0; kc < 4; kc++) {
      const int c0 = kc*32 + quad*8;
      float4 v0 = *(const float4*)(prow + c0);
      float4 v1 = *(const float4*)(prow + c0 + 4);
      float e[8] = {v0.x, v0.y, v0.z, v0.w, v1.x, v1.y, v1.z, v1.w};
      u16x8 hh;
      #pragma unroll
      for (int j = 0; j < 8; j++) {
        float z = (e[j] - mP) * rP;
        z = ((z >= 0.f) ? z : 0.01f*z) * riA[kc][j];
        hh[j] = f2bf(z);
      }
      af[kc] = __builtin_bit_cast(bf16x8, hh);
    }

    #pragma unroll 2
    for (int tj = 0; tj < 10; tj++) {
      f32x4 acc = {0.f, 0.f, 0.f, 0.f};
      #pragma unroll
      for (int kc = 0; kc < 4; kc++) {
        int row = tj*16 + l16;
        row = (row < NW) ? row : (NW-1);
        unsigned int off = (unsigned int)(row*256 + (kc*32+quad*8)*2)
                         ^ (unsigned int)((row&7)<<4);
        bf16x8 bf = *(const bf16x8*)((const char*)Ql + off);
        acc = __builtin_amdgcn_mfma_f32_16x16x32_bf16(af[kc], bf, acc, 0, 0, 0);
      }
      const int col = tj*16 + l16;
      if (col < NW) {
        #pragma unroll
        for (int r = 0; r < 4; r++)
          stg[(quad*4 + r)*154 + col] = acc[r];
      }
    }
    // per-wave write of the 16-row strip; rows are contiguous 604B streams
    for (int r = 0; r < 16; r++) {
      const int mm = mbase + r;
      if (mm >= NW) break;
      const int orow = 1 + invs[mm];
      float* dst = ob + (size_t)orow*NW;
      for (int col = lane; col < NW; col += 64) {
        float v = stg[r*154 + col] * 100.f;
        if (col == mm) { ob[mm] = v; v = NEG_BIG; }
        dst[col] = v;
      }
    }
  }
}

// ---------------------------------------------------------------------------
extern "C" void kernel_launch(void* const* d_in, const int* in_sizes, int n_in,
                              void* d_out, int out_size, void* d_ws, size_t ws_size,
                              hipStream_t stream) {
  const float* x   = (const float*)d_in[0];
  const float* gW0 = (const float*)d_in[1];
  const float* gW1 = (const float*)d_in[2];
  const float* gW2 = (const float*)d_in[3];
  const float* fW0 = (const float*)d_in[4];
  const float* fW1 = (const float*)d_in[5];
  const float* fW2 = (const float*)d_in[6];
  const int*  perm = (const int*)d_in[7];
  float* out = (float*)d_out;
  char* ws = (char*)d_ws;

  float* stats = (float*)ws;                       // 6 x 302 floats
  int*   inv   = (int*)(ws + 8192);
  float* rinvP = (float*)(ws + 16384);             // 2048*128 (used late)
  float* rinvQ = rinvP + 2048*128;
  float* Ag = (float*)(ws + 16384 + 2*1048576);    // h1g: 2048*151*50
  float* Bg = Ag + 15462400;                       // h2g: 2048*151*25
  float* Cg = Bg + 7731200;                        // h3g (raw)
  float* Df = Cg + 39583744;                       // h1f: 2048*151*100
  float* Ff = Df + 30924800;                       // h3f (raw)
  float* Ef = Ag;                                  // h2f reuses dead h1g

  // split-bf16 weights live in the rinvP area (dead until normstats_k):
  unsigned short* Wbase = (unsigned short*)(ws + 16384);
  unsigned short* Wg1 = Wbase;            // 64x64   -> 2*4096
  unsigned short* Wg2 = Wbase + 8192;     // 32x64   -> 2*2048
  unsigned short* Wg3 = Wbase + 12288;    // 128x32  -> 2*4096
  unsigned short* Wf2 = Wbase + 20480;    // 64x128  -> 2*8192
  unsigned short* Wf3 = Wbase + 36864;    // 128x64  -> 2*8192  (ends 53248)

  float* sg1 = stats,        *sg2 = stats + 302,  *sg3 = stats + 604;
  float* sf1 = stats + 906,  *sf2 = stats + 1208, *sf3 = stats + 1510;

  hipMemsetAsync(stats, 0, 1812*sizeof(float), stream);
  invperm_k<<<1, 192, 0, stream>>>(perm, inv);

  // weight pre-conversion (tiny)
  wcvt_k<<<16, 256, 0, stream>>>(gW0, Wg1,  50,  50,  64, 4096);
  wcvt_k<<< 8, 256, 0, stream>>>(gW1, Wg2,  25,  50,  64, 2048);
  wcvt_k<<<16, 256, 0, stream>>>(gW2, Wg3, 128,  25,  32, 4096);
  wcvt_k<<<32, 256, 0, stream>>>(fW1, Wf2,  50, 100, 128, 8192);
  wcvt_k<<<32, 256, 0, stream>>>(fW2, Wf3, 128,  50,  64, 8192);

  // f layer 1 via sliding-window scan + separate stats pass
  f1scan_k<<<dim3(BB/4, 2), 256, 0, stream>>>(x, fW0, Df);
  bnstats_k<100><<<dim3(NW, 8), 256, 0, stream>>>(Df, sf1);

  dim3 gl2(NW, BB/128);
  layer_mfma_k< 50,  50, 0, 0><<<gl2, 256, 0, stream>>>(x,  Wg1, nullptr, Ag, sg1);
  layer_mfma_k< 50,  25, 2, 1><<<gl2, 256, 0, stream>>>(Ag, Wg2, sg1,     Bg, sg2);
  layer_mfma_k< 25, 128, 2, 1><<<gl2, 256, 0, stream>>>(Bg, Wg3, sg2,     Cg, sg3);
  layer_mfma_k<100,  50, 2, 2><<<gl2, 256, 0, stream>>>(Df, Wf2, sf1,     Ef, sf2);
  layer_mfma_k< 50, 128, 2, 1><<<gl2, 256, 0, stream>>>(Ef, Wf3, sf2,     Ff, sf3);

  // per-(b,d) inverse norms
  normstats_k<<<1024, 256, 0, stream>>>(Cg, sg3, rinvP);
  normstats_k<<<1024, 256, 0, stream>>>(Ff, sf3, rinvQ);

  // fused normalize + einsum + masked scatter
  fusedfinal_k<<<BB, 256, 0, stream>>>(Cg, Ff, sg3, sf3, rinvP, rinvQ, inv, out);
  (void)in_sizes; (void)n_in; (void)out_size; (void)ws_size;
}

// Round 6
// 800.801 us; speedup vs baseline: 1.4510x; 1.0512x over previous
//
#include <hip/hip_runtime.h>
#include <math.h>
#include <string.h>

// ---------------- problem constants ----------------
constexpr int BB   = 2048;   // batch
constexpr int NW   = 151;    // windows
constexpr int NF   = 200;    // features
constexpr float BN_EPS = 1e-5f;

typedef __bf16 bf16x8 __attribute__((ext_vector_type(8)));
typedef float  f32x4  __attribute__((ext_vector_type(4)));
typedef unsigned short u16x8 __attribute__((ext_vector_type(8)));

__device__ __forceinline__ unsigned short f2bf(float f) {
  unsigned int u; memcpy(&u, &f, 4);
  unsigned int r = (u + 0x7FFFu + ((u >> 16) & 1u)) >> 16;   // RNE
  return (unsigned short)r;
}
__device__ __forceinline__ float bf2f(unsigned short u) {
  unsigned int x = ((unsigned int)u) << 16;
  float f; memcpy(&f, &x, 4);
  return f;
}

// ---------------------------------------------------------------------------
// f layer 1 via sliding-window recurrence:
//   h[b,0,c]   = sum_i W[c,i] * x[b, i+50]
//   h[b,n+1,c] = h[b,n,c] + W[c,n] * (x[b,n] - x[b,n+50])
// ---------------------------------------------------------------------------
__global__ __launch_bounds__(256) void f1scan_k(
  const float* __restrict__ x, const float* __restrict__ W,
  float* __restrict__ Df)
{
  __shared__ float Wt[150*51];
  __shared__ float xs[800];
  __shared__ float lso[3200];
  const int t  = threadIdx.x;
  const int b0 = blockIdx.x * 4;
  const int ch = blockIdx.y;
  const int bl = t >> 6;
  const int c  = t & 63;

  for (int idx = t; idx < 50*150; idx += 256) {
    int cl = idx / 150, k = idx % 150;
    Wt[k*51 + cl] = W[(ch*50 + cl)*150 + k];
  }
  for (int idx = t; idx < 800; idx += 256) {
    int b2 = idx / 200, j = idx % 200;
    xs[idx] = x[(b0 + b2)*200 + j];
  }
  __syncthreads();

  float h = 0.f;
  if (c < 50) {
    #pragma unroll 5
    for (int i = 0; i < 150; i++)
      h += Wt[i*51 + c] * xs[bl*200 + 50 + i];
  }

  for (int n0 = 0; n0 < NW; n0 += 16) {
    const int cs = (NW - n0 < 16) ? (NW - n0) : 16;
    if (c < 50) {
      for (int l = 0; l < cs; l++) {
        int n = n0 + l;
        lso[bl*800 + l*50 + c] = h;
        if (n < 150) h += Wt[n*51 + c] * (xs[bl*200 + n] - xs[bl*200 + n + 50]);
      }
    }
    __syncthreads();
    const int tot = 4*cs*50;
    for (int idx = t; idx < tot; idx += 256) {
      int b2 = idx / (cs*50), rem = idx % (cs*50);
      int l = rem / 50, cc = rem % 50;
      Df[((size_t)(b0+b2)*NW + n0 + l)*100 + ch*50 + cc] = lso[b2*800 + l*50 + cc];
    }
    __syncthreads();
  }
}

// ---------------------------------------------------------------------------
// Per-window BN stats (sum, sumsq) over (b, c).
// ---------------------------------------------------------------------------
template<int C>
__global__ __launch_bounds__(256) void bnstats_k(
  const float* __restrict__ H, float* __restrict__ stats)
{
  __shared__ float red[8];
  const int n = blockIdx.x, b0 = blockIdx.y * 256, t = threadIdx.x;
  float s1 = 0.f, s2 = 0.f;
  for (int idx = t; idx < 256*C; idx += 256) {
    int b = b0 + idx / C, cc = idx % C;
    float v = H[((size_t)b*NW + n)*C + cc];
    s1 += v; s2 += v*v;
  }
  #pragma unroll
  for (int off = 32; off; off >>= 1) {
    s1 += __shfl_down(s1, off); s2 += __shfl_down(s2, off);
  }
  if ((t & 63) == 0) { red[(t>>6)*2] = s1; red[(t>>6)*2+1] = s2; }
  __syncthreads();
  if (t == 0) {
    atomicAdd(&stats[2*n],   red[0]+red[2]+red[4]+red[6]);
    atomicAdd(&stats[2*n+1], red[1]+red[3]+red[5]+red[7]);
  }
}

// ---------------------------------------------------------------------------
// Weight pre-conversion: fp32 W[OUT][IN] -> padded split-bf16 Wb.
// ---------------------------------------------------------------------------
__global__ __launch_bounds__(256) void wcvt_k(
  const float* __restrict__ W, unsigned short* __restrict__ Wb,
  int OUT, int IN, int KP, int total)
{
  int idx = blockIdx.x*256 + threadIdx.x;
  if (idx >= total) return;
  int o = idx / KP, k = idx % KP;
  float v = (o < OUT && k < IN) ? W[o*IN + k] : 0.f;
  unsigned short hi = f2bf(v);
  float lo = v - bf2f(hi);
  Wb[idx] = hi;
  Wb[total + idx] = f2bf(lo);
}

// ---------------------------------------------------------------------------
// MFMA layer: per (window n, 128-batch chunk):  H = act(bn(X)) @ W^T
// LDS-free; split-bf16 (hi/lo) x3 MFMAs for ~fp32 accuracy.
// ---------------------------------------------------------------------------
template<int IN, int OUT, int MODE, int ACT>
__global__ __launch_bounds__(256) void layer_mfma_k(
    const float* __restrict__ X, const unsigned short* __restrict__ Wb,
    const float* __restrict__ statsPrev, float* __restrict__ H,
    float* __restrict__ statsOut)
{
  constexpr int KP   = (IN + 31) & ~31;    // K padded to 32
  constexpr int OUTP = (OUT + 15) & ~15;   // N padded to 16
  constexpr int KC   = KP / 32;
  constexpr int NT   = OUTP / 16;
  constexpr int MT   = 2;                  // m-tiles per wave

  __shared__ float red[8];
  const int n    = blockIdx.x;
  const int b0   = blockIdx.y * 128;
  const int t    = threadIdx.x;
  const int w    = t >> 6;
  const int lane = t & 63;
  const int l16  = lane & 15;
  const int quad = lane >> 4;

  float mean = 0.f, rstd = 1.f;
  if constexpr (MODE == 2) {
    const float cnt = (float)BB * (float)IN;
    mean = statsPrev[2*n] / cnt;
    float var = statsPrev[2*n+1] / cnt - mean*mean;
    rstd = rsqrtf(var + BN_EPS);
  }

  bf16x8 af_hi[MT][KC], af_lo[MT][KC];
  #pragma unroll
  for (int mt = 0; mt < MT; mt++) {
    const int bb = b0 + (w*MT + mt)*16 + l16;
    const float* xr = (MODE == 0)
        ? (X + (size_t)bb*NF + n)
        : (X + ((size_t)bb*NW + n)*IN);
    #pragma unroll
    for (int kc = 0; kc < KC; kc++) {
      const int k0 = kc*32 + quad*8;
      float vv[8];
      if constexpr (MODE == 0) {
        #pragma unroll
        for (int j = 0; j < 8; j++) {
          int k = k0 + j;
          vv[j] = (k < IN) ? xr[k] : 0.f;
        }
      } else if constexpr (IN % 4 == 0) {
        #pragma unroll
        for (int g = 0; g < 2; g++) {
          int kg = k0 + 4*g;
          if (kg < IN) {
            float4 f = *(const float4*)(xr + kg);
            vv[4*g] = f.x; vv[4*g+1] = f.y; vv[4*g+2] = f.z; vv[4*g+3] = f.w;
          } else {
            vv[4*g] = 0.f; vv[4*g+1] = 0.f; vv[4*g+2] = 0.f; vv[4*g+3] = 0.f;
          }
        }
      } else if constexpr (IN % 2 == 0) {
        #pragma unroll
        for (int g = 0; g < 4; g++) {
          int kg = k0 + 2*g;
          if (kg < IN) {
            float2 f = *(const float2*)(xr + kg);
            vv[2*g] = f.x; vv[2*g+1] = f.y;
          } else {
            vv[2*g] = 0.f; vv[2*g+1] = 0.f;
          }
        }
      } else {
        #pragma unroll
        for (int j = 0; j < 8; j++) {
          int k = k0 + j;
          vv[j] = (k < IN) ? xr[k] : 0.f;
        }
      }
      u16x8 hi, lo;
      #pragma unroll
      for (int j = 0; j < 8; j++) {
        bool valid = (k0 + j) < IN;
        float v;
        if constexpr (MODE == 0) {
          v = vv[j];
        } else {
          float z = (vv[j] - mean) * rstd;
          float a = (ACT == 1) ? ((z >= 0.f) ? z : 0.01f*z) : tanhf(z);
          v = valid ? a : 0.f;
        }
        unsigned short h16 = f2bf(v);
        hi[j] = h16;
        lo[j] = f2bf(v - bf2f(h16));
      }
      af_hi[mt][kc] = __builtin_bit_cast(bf16x8, hi);
      af_lo[mt][kc] = __builtin_bit_cast(bf16x8, lo);
    }
  }

  float s1 = 0.f, s2 = 0.f;
  #pragma unroll
  for (int nt = 0; nt < NT; nt++) {
    const int c = nt*16 + l16;
    f32x4 acc[MT];
    #pragma unroll
    for (int mt = 0; mt < MT; mt++) acc[mt] = (f32x4){0.f, 0.f, 0.f, 0.f};
    #pragma unroll
    for (int kc = 0; kc < KC; kc++) {
      const unsigned short* wp = Wb + (size_t)(nt*16 + l16)*KP + kc*32 + quad*8;
      bf16x8 wh = *(const bf16x8*)wp;
      bf16x8 wl = *(const bf16x8*)(wp + OUTP*KP);
      #pragma unroll
      for (int mt = 0; mt < MT; mt++) {
        acc[mt] = __builtin_amdgcn_mfma_f32_16x16x32_bf16(af_hi[mt][kc], wh, acc[mt], 0, 0, 0);
        acc[mt] = __builtin_amdgcn_mfma_f32_16x16x32_bf16(af_lo[mt][kc], wh, acc[mt], 0, 0, 0);
        acc[mt] = __builtin_amdgcn_mfma_f32_16x16x32_bf16(af_hi[mt][kc], wl, acc[mt], 0, 0, 0);
      }
    }
    #pragma unroll
    for (int mt = 0; mt < MT; mt++) {
      const int mrow = (w*MT + mt)*16 + quad*4;
      #pragma unroll
      for (int r = 0; r < 4; r++) {
        float v = acc[mt][r];
        s1 += v; s2 += v*v;
        if (c < OUT)
          H[((size_t)(b0 + mrow + r)*NW + n)*OUT + c] = v;
      }
    }
  }

  #pragma unroll
  for (int off = 32; off; off >>= 1) {
    s1 += __shfl_down(s1, off); s2 += __shfl_down(s2, off);
  }
  if (lane == 0) { red[w*2] = s1; red[w*2+1] = s2; }
  __syncthreads();
  if (t == 0) {
    atomicAdd(&statsOut[2*n],   red[0]+red[2]+red[4]+red[6]);
    atomicAdd(&statsOut[2*n+1], red[1]+red[3]+red[5]+red[7]);
  }
}

// ---------------------------------------------------------------------------
// Precompute BN (mean, rstd) tables for the two layer-3 stat vectors.
// Identical arithmetic to the previous in-kernel computation.
// ---------------------------------------------------------------------------
__global__ void mr_k(const float* __restrict__ sP, const float* __restrict__ sQ,
                     float* __restrict__ mrP, float* __restrict__ mrQ)
{
  int n = threadIdx.x;
  if (n >= NW) return;
  const float cnt = (float)BB * 128.f;
  float m = sP[2*n] / cnt;
  float var = sP[2*n+1] / cnt - m*m;
  mrP[2*n] = m; mrP[2*n+1] = rsqrtf(var + BN_EPS);
  m = sQ[2*n] / cnt;
  var = sQ[2*n+1] / cnt - m*m;
  mrQ[2*n] = m; mrQ[2*n+1] = rsqrtf(var + BN_EPS);
}

// ---------------------------------------------------------------------------
// Per-(b,d): 1/max(||leaky(bn(h3))||_n, 1e-12)   (uses precomputed (m,r))
// ---------------------------------------------------------------------------
__global__ __launch_bounds__(256) void normstats_k(
  const float* __restrict__ H, const float* __restrict__ mr,
  float* __restrict__ rinv)
{
  int idx = blockIdx.x*256 + threadIdx.x;   // over B*128
  int b = idx >> 7, d = idx & 127;
  float s = 0.f;
  for (int n = 0; n < NW; n++) {
    float m = mr[2*n];
    float r = mr[2*n+1];
    float v = H[((size_t)b*NW + n)*128 + d];
    float z = (v - m) * r;
    float lv = (z >= 0.f) ? z : 0.01f*z;
    s += lv*lv;
  }
  rinv[idx] = 1.f / fmaxf(sqrtf(s), 1e-12f);
}

__global__ void invperm_k(const int* __restrict__ perm, int* __restrict__ inv) {
  int j = threadIdx.x;
  if (j < NW) inv[perm[j]] = j;
}

// ---------------------------------------------------------------------------
// Fused normalize + final einsum. One block per batch element b.
//  - Q tile stored in LDS in MFMA-FRAGMENT ORDER: fragment f = tj*4+kc holds
//    16B per lane at ((f*64 + lane)*16) -> both the phase-1 ds_write_b128 and
//    every phase-2 ds_read_b128 are perfectly linear in lane (conflict-free).
//    Wave w fills kc-column w (its per-lane rinvQ slice is loop-invariant).
//    Pad rows (n >= NW) are written as zeros.
//  - A-fragments built per-strip straight from global fp32 (BN+leaky+rinv
//    via precomputed (m,r) tables; identical numerics).
//  - Output strips staged in per-wave LDS (stride 154 -> 2-way, free) then
//    written as contiguous 604B row streams.
// LDS total ~81 KB -> 2 blocks/CU.
// ---------------------------------------------------------------------------
__global__ __launch_bounds__(256) void fusedfinal_k(
  const float* __restrict__ P32, const float* __restrict__ Q32,
  const float* __restrict__ mrP, const float* __restrict__ mrQ,
  const float* __restrict__ rinvP, const float* __restrict__ rinvQ,
  const int* __restrict__ inv, float* __restrict__ out)
{
  __shared__ unsigned short Qf[40*64*8];   // 40960 B, fragment-ordered
  __shared__ float stgbuf[4][16*154];      // 39424 B per-wave strip staging
  __shared__ int invs[NW];

  const int b    = blockIdx.x;
  const int t    = threadIdx.x;
  const int w    = t >> 6;
  const int lane = t & 63;
  const int l16  = lane & 15;
  const int quad = lane >> 4;

  for (int i = t; i < NW; i += 256) invs[i] = inv[i];

  // ---- phase 1: fill Q bf16 fragments (BN + leaky + rinv + f2bf) ----
  {
    const int kcw = w;                       // wave w owns kc column w
    const int c0  = kcw*32 + quad*8;
    float ri[8];
    {
      float4 r0 = *(const float4*)&rinvQ[(b<<7) + c0];
      float4 r1 = *(const float4*)&rinvQ[(b<<7) + c0 + 4];
      ri[0]=r0.x; ri[1]=r0.y; ri[2]=r0.z; ri[3]=r0.w;
      ri[4]=r1.x; ri[5]=r1.y; ri[6]=r1.z; ri[7]=r1.w;
    }
    #pragma unroll
    for (int tj = 0; tj < 10; tj++) {
      const int n = tj*16 + l16;
      u16x8 hh;
      if (n < NW) {
        const float mQ = mrQ[2*n];
        const float rQ = mrQ[2*n+1];
        const float* qrow = Q32 + ((size_t)b*NW + n)*128 + c0;
        float4 u0 = *(const float4*)qrow;
        float4 u1 = *(const float4*)(qrow + 4);
        float e[8] = {u0.x, u0.y, u0.z, u0.w, u1.x, u1.y, u1.z, u1.w};
        #pragma unroll
        for (int j = 0; j < 8; j++) {
          float z = (e[j] - mQ) * rQ;
          z = ((z >= 0.f) ? z : 0.01f*z) * ri[j];
          hh[j] = f2bf(z);
        }
      } else {
        #pragma unroll
        for (int j = 0; j < 8; j++) hh[j] = 0;
      }
      *(bf16x8*)(Qf + ((size_t)(tj*4 + kcw)*64 + lane)*8) =
          __builtin_bit_cast(bf16x8, hh);
    }
  }
  __syncthreads();

  // per-lane rinvP slice for A-fragment columns (fixed by quad)
  float riA[4][8];
  #pragma unroll
  for (int kc = 0; kc < 4; kc++) {
    const int c0 = kc*32 + quad*8;
    float4 r0 = *(const float4*)&rinvP[(b<<7) + c0];
    float4 r1 = *(const float4*)&rinvP[(b<<7) + c0 + 4];
    riA[kc][0]=r0.x; riA[kc][1]=r0.y; riA[kc][2]=r0.z; riA[kc][3]=r0.w;
    riA[kc][4]=r1.x; riA[kc][5]=r1.y; riA[kc][6]=r1.z; riA[kc][7]=r1.w;
  }

  // ---- phase 2+3: MFMA strips + staged contiguous row writes ----
  float* ob = out + (size_t)b*152*NW;
  float* stg = stgbuf[w];
  const float NEG_BIG = -3.0e38f;

  for (int ti = w; ti < 10; ti += 4) {
    const int mbase = ti*16;
    // A-fragment: global fp32 row -> BN + leaky + rinv -> bf16 (in regs)
    const int arow = (mbase + l16 < NW) ? (mbase + l16) : (NW-1);
    const float mP = mrP[2*arow];
    const float rP = mrP[2*arow+1];
    const float* prow = P32 + ((size_t)b*NW + arow)*128;
    bf16x8 af[4];
    #pragma unroll
    for (int kc = 0; kc < 4; kc++) {
      const int c0 = kc*32 + quad*8;
      float4 v0 = *(const float4*)(prow + c0);
      float4 v1 = *(const float4*)(prow + c0 + 4);
      float e[8] = {v0.x, v0.y, v0.z, v0.w, v1.x, v1.y, v1.z, v1.w};
      u16x8 hh;
      #pragma unroll
      for (int j = 0; j < 8; j++) {
        float z = (e[j] - mP) * rP;
        z = ((z >= 0.f) ? z : 0.01f*z) * riA[kc][j];
        hh[j] = f2bf(z);
      }
      af[kc] = __builtin_bit_cast(bf16x8, hh);
    }

    #pragma unroll 2
    for (int tj = 0; tj < 10; tj++) {
      f32x4 acc = {0.f, 0.f, 0.f, 0.f};
      #pragma unroll
      for (int kc = 0; kc < 4; kc++) {
        bf16x8 bf = *(const bf16x8*)(Qf + ((size_t)(tj*4 + kc)*64 + lane)*8);
        acc = __builtin_amdgcn_mfma_f32_16x16x32_bf16(af[kc], bf, acc, 0, 0, 0);
      }
      const int col = tj*16 + l16;
      if (col < NW) {
        #pragma unroll
        for (int r = 0; r < 4; r++)
          stg[(quad*4 + r)*154 + col] = acc[r];
      }
    }
    // per-wave write of the 16-row strip; rows are contiguous 604B streams
    for (int r = 0; r < 16; r++) {
      const int mm = mbase + r;
      if (mm >= NW) break;
      const int orow = 1 + invs[mm];
      float* dst = ob + (size_t)orow*NW;
      for (int col = lane; col < NW; col += 64) {
        float v = stg[r*154 + col] * 100.f;
        if (col == mm) { ob[mm] = v; v = NEG_BIG; }
        dst[col] = v;
      }
    }
  }
}

// ---------------------------------------------------------------------------
extern "C" void kernel_launch(void* const* d_in, const int* in_sizes, int n_in,
                              void* d_out, int out_size, void* d_ws, size_t ws_size,
                              hipStream_t stream) {
  const float* x   = (const float*)d_in[0];
  const float* gW0 = (const float*)d_in[1];
  const float* gW1 = (const float*)d_in[2];
  const float* gW2 = (const float*)d_in[3];
  const float* fW0 = (const float*)d_in[4];
  const float* fW1 = (const float*)d_in[5];
  const float* fW2 = (const float*)d_in[6];
  const int*  perm = (const int*)d_in[7];
  float* out = (float*)d_out;
  char* ws = (char*)d_ws;

  float* stats = (float*)ws;                       // 6 x 302 floats
  int*   inv   = (int*)(ws + 8192);                // 604 B
  float* mrP   = (float*)(ws + 10240);             // 302 floats
  float* mrQ   = (float*)(ws + 11648);             // 302 floats
  float* rinvP = (float*)(ws + 16384);             // 2048*128 (used late)
  float* rinvQ = rinvP + 2048*128;
  float* Ag = (float*)(ws + 16384 + 2*1048576);    // h1g: 2048*151*50
  float* Bg = Ag + 15462400;                       // h2g: 2048*151*25
  float* Cg = Bg + 7731200;                        // h3g (raw)
  float* Df = Cg + 39583744;                       // h1f: 2048*151*100
  float* Ff = Df + 30924800;                       // h3f (raw)
  float* Ef = Ag;                                  // h2f reuses dead h1g

  // split-bf16 weights live in the rinvP area (dead until normstats_k):
  unsigned short* Wbase = (unsigned short*)(ws + 16384);
  unsigned short* Wg1 = Wbase;            // 64x64   -> 2*4096
  unsigned short* Wg2 = Wbase + 8192;     // 32x64   -> 2*2048
  unsigned short* Wg3 = Wbase + 12288;    // 128x32  -> 2*4096
  unsigned short* Wf2 = Wbase + 20480;    // 64x128  -> 2*8192
  unsigned short* Wf3 = Wbase + 36864;    // 128x64  -> 2*8192  (ends 53248)

  float* sg1 = stats,        *sg2 = stats + 302,  *sg3 = stats + 604;
  float* sf1 = stats + 906,  *sf2 = stats + 1208, *sf3 = stats + 1510;

  hipMemsetAsync(stats, 0, 1812*sizeof(float), stream);
  invperm_k<<<1, 192, 0, stream>>>(perm, inv);

  // weight pre-conversion (tiny)
  wcvt_k<<<16, 256, 0, stream>>>(gW0, Wg1,  50,  50,  64, 4096);
  wcvt_k<<< 8, 256, 0, stream>>>(gW1, Wg2,  25,  50,  64, 2048);
  wcvt_k<<<16, 256, 0, stream>>>(gW2, Wg3, 128,  25,  32, 4096);
  wcvt_k<<<32, 256, 0, stream>>>(fW1, Wf2,  50, 100, 128, 8192);
  wcvt_k<<<32, 256, 0, stream>>>(fW2, Wf3, 128,  50,  64, 8192);

  // f layer 1 via sliding-window scan + separate stats pass
  f1scan_k<<<dim3(BB/4, 2), 256, 0, stream>>>(x, fW0, Df);
  bnstats_k<100><<<dim3(NW, 8), 256, 0, stream>>>(Df, sf1);

  dim3 gl2(NW, BB/128);
  layer_mfma_k< 50,  50, 0, 0><<<gl2, 256, 0, stream>>>(x,  Wg1, nullptr, Ag, sg1);
  layer_mfma_k< 50,  25, 2, 1><<<gl2, 256, 0, stream>>>(Ag, Wg2, sg1,     Bg, sg2);
  layer_mfma_k< 25, 128, 2, 1><<<gl2, 256, 0, stream>>>(Bg, Wg3, sg2,     Cg, sg3);
  layer_mfma_k<100,  50, 2, 2><<<gl2, 256, 0, stream>>>(Df, Wf2, sf1,     Ef, sf2);
  layer_mfma_k< 50, 128, 2, 1><<<gl2, 256, 0, stream>>>(Ef, Wf3, sf2,     Ff, sf3);

  // (mean, rstd) tables for the layer-3 BN (used by all downstream kernels)
  mr_k<<<1, 192, 0, stream>>>(sg3, sf3, mrP, mrQ);

  // per-(b,d) inverse norms
  normstats_k<<<1024, 256, 0, stream>>>(Cg, mrP, rinvP);
  normstats_k<<<1024, 256, 0, stream>>>(Ff, mrQ, rinvQ);

  // fused normalize + einsum + masked scatter
  fusedfinal_k<<<BB, 256, 0, stream>>>(Cg, Ff, mrP, mrQ, rinvP, rinvQ, inv, out);
  (void)in_sizes; (void)n_in; (void)out_size; (void)ws_size;
}